// Round 4
// baseline (5646.547 us; speedup 1.0000x reference)
//
#include <hip/hip_runtime.h>
#include <stdint.h>
#include <math.h>

#define NIN    784
#define H1     100
#define H2     10
#define BATCH  4096
#define KC     28        // K-chunk size
#define NCH    28        // 784/28
#define RT     16        // rows per block (contiguous)
#define NSTEP  99        // t = 0..98 (layer2 runs 0..98; layer1 0..97)

// ---- Threefry-2x32 core, matching jax._src.prng ----
__device__ __forceinline__ void threefry2x32(uint32_t k0, uint32_t k1,
                                             uint32_t x0, uint32_t x1,
                                             uint32_t& o0, uint32_t& o1) {
    uint32_t ks2 = k0 ^ k1 ^ 0x1BD11BDAu;
    x0 += k0; x1 += k1;
#define TFR(r) { x0 += x1; x1 = (x1 << (r)) | (x1 >> (32 - (r))); x1 ^= x0; }
    TFR(13) TFR(15) TFR(26) TFR(6)  x0 += k1;  x1 += ks2 + 1u;
    TFR(17) TFR(29) TFR(16) TFR(24) x0 += ks2; x1 += k0 + 2u;
    TFR(13) TFR(15) TFR(26) TFR(6)  x0 += k0;  x1 += k1 + 3u;
    TFR(17) TFR(29) TFR(16) TFR(24) x0 += k1;  x1 += ks2 + 4u;
    TFR(13) TFR(15) TFR(26) TFR(6)  x0 += ks2; x1 += k0 + 5u;
#undef TFR
    o0 = x0; o1 = x1;
}

__device__ __forceinline__ float u01(uint32_t b) {
    return __uint_as_float((b >> 9) | 0x3f800000u) - 1.0f;
}

__global__ __launch_bounds__(256)
void spiking_net_kernel(const float* __restrict__ x,
                        const float* __restrict__ W1,
                        const float* __restrict__ b1,
                        const float* __restrict__ W2,
                        const float* __restrict__ b2,
                        float* __restrict__ out) {
    __shared__ float    w1buf[2][KC * H1];   // 22400 B, double-buffered W1 chunks (f32: exact widen)
    __shared__ double   xibuf[2][RT * KC];   //  7168 B, gated inputs as f64
    __shared__ double   o1s[RT * H1];        // 12800 B, prev-step outer1 (f64)
    __shared__ float    w2s[H1 * H2];        //  4000 B
    __shared__ uint32_t keys[200];           //   800 B, interleaved (k0_t, k1_t)
    __shared__ double   sums[RT * H2];       //  1280 B
    // total 48448 B

    const int tid  = threadIdx.x;
    const int bidx = blockIdx.x;
    const int wave = tid >> 6;
    const int lane = tid & 63;
    const int row0 = bidx * RT;              // block owns rows [row0, row0+16)

    // ---- init: partitionable ("foldlike") split(key(42), 100):
    //      key_t = threefry((0,42), (hi=0, lo=t)), both output words ----
    if (tid < 100) {
        uint32_t y0, y1;
        threefry2x32(0u, 42u, 0u, (uint32_t)tid, y0, y1);
        keys[2 * tid] = y0; keys[2 * tid + 1] = y1;
    }
    for (int i = tid; i < H1 * H2; i += 256) w2s[i] = W2[i];
    for (int i = tid; i < RT * H1; i += 256) o1s[i] = 0.0;

    // per-lane layer1 output-neuron assignment: h0 = lane, h1 = lane+64
    const int  h0  = lane;
    const bool h1v = (64 + lane < H1);
    const int  h1  = h1v ? (64 + lane) : (H1 - 1);
    const double b1_0 = (double)b1[h0];
    const double b1_1 = (double)b1[h1];

    double i1[4][2] = {{0.,0.},{0.,0.},{0.,0.},{0.,0.}};

    // layer2: thread (r2, c2) for tid < 160
    const int  r2    = tid / 10;
    const int  c2    = tid - r2 * 10;
    const bool l2act = (tid < RT * H2);
    const double b2r = l2act ? (double)b2[c2] : 0.0;
    double i2 = 0.0, sum2 = 0.0;

    __syncthreads();

    auto w1_prefetch = [&](int c, int buf) {
        const float4* src = (const float4*)(W1 + c * (KC * H1));
        float4* dst = (float4*)w1buf[buf];
        for (int i = tid; i < (KC * H1) / 4; i += 256) dst[i] = src[i];
    };
    // Partitionable random_bits: per flat element e of the (4096,784) draw,
    // (b1,b2) = threefry(key_t, (hi=0, lo=e)); bits = b1 ^ b2.
    auto gen_chunk = [&](int c, int buf, uint32_t k0, uint32_t k1) {
        const int j0 = c * KC;
        for (int e = tid; e < RT * KC; e += 256) {        // 448 elements
            int r  = e / KC;
            int jj = e - r * KC;
            uint32_t ctr = (uint32_t)((row0 + r) * NIN + j0 + jj);
            uint32_t y0, y1;
            threefry2x32(k0, k1, 0u, ctr, y0, y1);
            double xv = (double)x[(row0 + r) * NIN + j0 + jj];
            xibuf[buf][r * KC + jj] = (double)u01(y0 ^ y1) * xv;
        }
    };

    double acc[4][2];

    for (int t = 0; t < NSTEP; ++t) {
        const uint32_t k0 = keys[2 * t];
        const uint32_t k1 = keys[2 * t + 1];
        const bool dol1 = (t < 98);          // layer1 only for t<98

        #pragma unroll
        for (int r = 0; r < 4; ++r) { acc[r][0] = 0.; acc[r][1] = 0.; }

        // ---- phase A: stage chunk0; layer2 on prev o1s ----
        if (dol1) {
            w1_prefetch(0, 0);
            gen_chunk(0, 0, k0, k1);
        }
        if (l2act) {
            const double* orow = &o1s[r2 * H1];
            double a = 0.0;
            #pragma unroll 4
            for (int k = 0; k < H1; ++k) a += orow[k] * (double)w2s[k * H2 + c2];
            double exc2   = a + b2r;
            double inner2 = exc2 + i2 * 0.9;
            double outer2 = fmax(inner2 - 1.0, 0.0);
            double pen2   = 1.5 * inner2;
            inner2 = (outer2 > 0.0) ? (inner2 - pen2) : inner2;
            i2 = inner2;
            if (t >= 19) sum2 += inner2;     // out = sum of post-update i2, t=19..98
        }
        __syncthreads();

        if (dol1) {
            for (int c = 0; c < NCH; ++c) {
                const int cb = c & 1;
                if (c + 1 < NCH) {
                    w1_prefetch(c + 1, cb ^ 1);
                    gen_chunk(c + 1, cb ^ 1, k0, k1);
                }
                const float*  wb  = w1buf[cb];
                const double* xr0 = &xibuf[cb][(4 * wave + 0) * KC];
                const double* xr1 = &xibuf[cb][(4 * wave + 1) * KC];
                const double* xr2 = &xibuf[cb][(4 * wave + 2) * KC];
                const double* xr3 = &xibuf[cb][(4 * wave + 3) * KC];
                #pragma unroll 4
                for (int jj = 0; jj < KC; ++jj) {
                    const double w0v = (double)wb[jj * H1 + h0];
                    const double w1v = (double)wb[jj * H1 + h1];
                    const double a0 = xr0[jj];
                    const double a1 = xr1[jj];
                    const double a2 = xr2[jj];
                    const double a3 = xr3[jj];
                    acc[0][0] = fma(a0, w0v, acc[0][0]);  acc[0][1] = fma(a0, w1v, acc[0][1]);
                    acc[1][0] = fma(a1, w0v, acc[1][0]);  acc[1][1] = fma(a1, w1v, acc[1][1]);
                    acc[2][0] = fma(a2, w0v, acc[2][0]);  acc[2][1] = fma(a2, w1v, acc[2][1]);
                    acc[3][0] = fma(a3, w0v, acc[3][0]);  acc[3][1] = fma(a3, w1v, acc[3][1]);
                }
                __syncthreads();
            }
            // ---- layer1 neuron update (f64), write outer1 for next step ----
            #pragma unroll
            for (int r = 0; r < 4; ++r) {
                const int lr = 4 * wave + r;
                double e0   = acc[r][0] + b1_0;
                double in0  = e0 + i1[r][0] * 0.9;
                double out0 = fmax(in0 - 1.0, 0.0);
                double pen0 = 1.5 * in0;
                in0 = (out0 > 0.0) ? (in0 - pen0) : in0;
                i1[r][0] = in0;
                o1s[lr * H1 + h0] = out0;

                double e1   = acc[r][1] + b1_1;
                double in1  = e1 + i1[r][1] * 0.9;
                double out1 = fmax(in1 - 1.0, 0.0);
                double pen1 = 1.5 * in1;
                in1 = (out1 > 0.0) ? (in1 - pen1) : in1;
                i1[r][1] = in1;
                if (h1v) o1s[lr * H1 + h1] = out1;
            }
        }
        __syncthreads();
    }

    // ---- epilogue: log_softmax (f64) ----
    if (l2act) sums[r2 * H2 + c2] = sum2;
    __syncthreads();
    if (l2act) {
        double m = -INFINITY;
        #pragma unroll
        for (int c = 0; c < H2; ++c) m = fmax(m, sums[r2 * H2 + c]);
        double s = 0.0;
        #pragma unroll
        for (int c = 0; c < H2; ++c) s += exp(sums[r2 * H2 + c] - m);
        const double lse = log(s);
        out[(row0 + r2) * H2 + c2] = (float)(sum2 - m - lse);
    }
}

extern "C" void kernel_launch(void* const* d_in, const int* in_sizes, int n_in,
                              void* d_out, int out_size, void* d_ws, size_t ws_size,
                              hipStream_t stream) {
    const float* x  = (const float*)d_in[0];
    const float* W1 = (const float*)d_in[1];
    const float* b1 = (const float*)d_in[2];
    const float* W2 = (const float*)d_in[3];
    const float* b2 = (const float*)d_in[4];
    float* out = (float*)d_out;
    // 256 blocks × 16 contiguous rows each (partitionable threefry: one hash
    // per element, counter = flat index — no low/high-half pairing).
    hipLaunchKernelGGL(spiking_net_kernel, dim3(BATCH / RT), dim3(256), 0, stream,
                       x, W1, b1, W2, b2, out);
}

// Round 5
// 2382.982 us; speedup vs baseline: 2.3695x; 2.3695x over previous
//
#include <hip/hip_runtime.h>
#include <stdint.h>
#include <math.h>

#define NIN    784
#define H1     100
#define H2     10
#define BATCH  4096
#define KC     28        // K-chunk (jj per chunk); 784 = 28*28
#define NCH    28
#define KCP    32        // xi row stride (b128-aligned)
#define RT     16        // rows per block
#define NSTEP  99        // layer2 t=0..98; layer1 t=0..97

// ---- Threefry-2x32 core (jax partitionable path verified R4) ----
__device__ __forceinline__ void threefry2x32(uint32_t k0, uint32_t k1,
                                             uint32_t x0, uint32_t x1,
                                             uint32_t& o0, uint32_t& o1) {
    uint32_t ks2 = k0 ^ k1 ^ 0x1BD11BDAu;
    x0 += k0; x1 += k1;
#define TFR(r) { x0 += x1; x1 = (x1 << (r)) | (x1 >> (32 - (r))); x1 ^= x0; }
    TFR(13) TFR(15) TFR(26) TFR(6)  x0 += k1;  x1 += ks2 + 1u;
    TFR(17) TFR(29) TFR(16) TFR(24) x0 += ks2; x1 += k0 + 2u;
    TFR(13) TFR(15) TFR(26) TFR(6)  x0 += k0;  x1 += k1 + 3u;
    TFR(17) TFR(29) TFR(16) TFR(24) x0 += k1;  x1 += ks2 + 4u;
    TFR(13) TFR(15) TFR(26) TFR(6)  x0 += ks2; x1 += k0 + 5u;
#undef TFR
    o0 = x0; o1 = x1;
}

__device__ __forceinline__ float u01(uint32_t b) {
    return __uint_as_float((b >> 9) | 0x3f800000u) - 1.0f;
}

// One-shot W1 transpose into workspace: w1t[h][jj] = W1[jj][h]
__global__ void transpose_w1(const float* __restrict__ W1, float* __restrict__ w1t) {
    int idx = blockIdx.x * 256 + threadIdx.x;
    if (idx < NIN * H1) {
        int h = idx / NIN, jj = idx - h * NIN;
        w1t[idx] = W1[jj * H1 + h];
    }
}

__global__ __launch_bounds__(1024)
void spiking_net_kernel(const float* __restrict__ x,
                        const float* __restrict__ w1t,
                        const float* __restrict__ b1,
                        const float* __restrict__ W2,
                        const float* __restrict__ b2,
                        float* __restrict__ out) {
    __shared__ __align__(16) float    wt[2][H1 * KC];    // 22400 B transposed W1 chunks
    __shared__ __align__(16) float    xib[2][RT * KCP];  //  4096 B gated inputs
    __shared__ __align__(16) float    o1s[RT * H1];      //  6400 B prev-step outer1
    __shared__ __align__(16) float    w2t[H2 * H1];      //  4000 B W2 transposed
    __shared__ __align__(16) float    red[3 * RT * 128]; // 24576 B partial-acc reduction
    __shared__ __align__(16) float    sums[RT * H2];     //   640 B
    __shared__           uint32_t keys[200];             //   800 B   (total 62912 B)

    const int tid  = threadIdx.x;
    const int wv   = tid >> 6;
    const int lane = tid & 63;
    const int g    = wv & 3;          // row-group: rows 4g..4g+3 (also = SIMD id)
    const int q    = wv >> 2;         // jj-quarter
    const int row0 = blockIdx.x * RT;

    if (tid < 100) {
        uint32_t y0, y1;
        threefry2x32(0u, 42u, 0u, (uint32_t)tid, y0, y1);
        keys[2 * tid] = y0; keys[2 * tid + 1] = y1;
    }
    for (int i = tid; i < H2 * H1; i += 1024) {
        int cc = i / H1, k = i - cc * H1;
        w2t[i] = W2[k * H2 + cc];
    }
    for (int i = tid; i < RT * H1; i += 1024) o1s[i] = 0.0f;

    // lane -> layer1 neurons h0=lane, h1=lane+64 (lanes>=36 idle on h1)
    const int  h0  = lane;
    const bool h1v = (lane < H1 - 64);
    const int  h1  = h1v ? (64 + lane) : (H1 - 1);
    const float b1_0 = b1[h0];
    const float b1_1 = b1[h1];
    float i1[4][2] = {{0,0},{0,0},{0,0},{0,0}};   // state held by q==0 waves

    const int  r2    = tid / 10;
    const int  c2    = tid - r2 * 10;
    const bool l2act = (tid < RT * H2);
    const float b2r  = l2act ? b2[c2] : 0.0f;
    float i2 = 0.0f, sum2 = 0.0f;

    __syncthreads();

    auto stage = [&](int c, int b) {
        for (int qd = tid; qd < H1 * (KC / 4); qd += 1024) {   // 700 float4
            int h = qd / (KC / 4), jq = qd - h * (KC / 4);
            *(float4*)&wt[b][h * KC + jq * 4] =
                *(const float4*)&w1t[h * NIN + c * KC + jq * 4];
        }
    };
    // waves 8..15 hash: e = (wv-8)*56 + lane, lane<56 -> 448 elems (16 rows x 28 jj)
    auto genxi = [&](int c, int b, uint32_t k0, uint32_t k1) {
        if (wv >= 8 && lane < 56) {
            int e  = (wv - 8) * 56 + lane;
            int r  = e / KC, jj = e - r * KC;
            uint32_t ctr = (uint32_t)((row0 + r) * NIN + c * KC + jj);
            uint32_t y0, y1;
            threefry2x32(k0, k1, 0u, ctr, y0, y1);
            xib[b][r * KCP + jj] = u01(y0 ^ y1) * x[ctr];
        }
    };

    float acc[4][2];
    const int jqb = 2 * q;
    const int jqe = (q == 3) ? 7 : (2 * q + 2);   // quarters: 2,2,2,1 jjq (balanced per SIMD)

    for (int t = 0; t < NSTEP; ++t) {
        const uint32_t k0 = keys[2 * t], k1 = keys[2 * t + 1];
        const bool dol1 = (t < 98);

        if (dol1) {
            stage(0, 0);
            genxi(0, 0, k0, k1);
            #pragma unroll
            for (int r = 0; r < 4; ++r) { acc[r][0] = 0.f; acc[r][1] = 0.f; }
        }
        if (l2act) {   // layer2 on prev-step o1s
            const float* orow = &o1s[r2 * H1];
            const float* wrow = &w2t[c2 * H1];
            float a = 0.0f;
            #pragma unroll
            for (int k = 0; k < H1; k += 4) {
                float4 ov = *(const float4*)&orow[k];
                float4 wq = *(const float4*)&wrow[k];
                a = fmaf(ov.x, wq.x, a); a = fmaf(ov.y, wq.y, a);
                a = fmaf(ov.z, wq.z, a); a = fmaf(ov.w, wq.w, a);
            }
            float inner2 = (a + b2r) + i2 * 0.9f;
            float outer2 = fmaxf(inner2 - 1.0f, 0.0f);
            inner2 = (outer2 > 0.0f) ? (inner2 - 1.5f * inner2) : inner2;
            i2 = inner2;
            if (t >= 19) sum2 += inner2;
        }
        __syncthreads();

        if (dol1) {
            for (int c = 0; c < NCH; ++c) {
                const int b = c & 1;
                if (c + 1 < NCH) { stage(c + 1, b ^ 1); genxi(c + 1, b ^ 1, k0, k1); }
                for (int jq = jqb; jq < jqe; ++jq) {
                    float4 w0  = *(const float4*)&wt[b][h0 * KC + jq * 4];
                    float4 w1q = *(const float4*)&wt[b][h1 * KC + jq * 4];
                    #pragma unroll
                    for (int r = 0; r < 4; ++r) {
                        float4 xq = *(const float4*)&xib[b][(4 * g + r) * KCP + jq * 4];
                        acc[r][0] = fmaf(xq.x, w0.x,  acc[r][0]);
                        acc[r][0] = fmaf(xq.y, w0.y,  acc[r][0]);
                        acc[r][0] = fmaf(xq.z, w0.z,  acc[r][0]);
                        acc[r][0] = fmaf(xq.w, w0.w,  acc[r][0]);
                        acc[r][1] = fmaf(xq.x, w1q.x, acc[r][1]);
                        acc[r][1] = fmaf(xq.y, w1q.y, acc[r][1]);
                        acc[r][1] = fmaf(xq.z, w1q.z, acc[r][1]);
                        acc[r][1] = fmaf(xq.w, w1q.w, acc[r][1]);
                    }
                }
                __syncthreads();
            }
            if (q > 0) {   // publish partial accumulators
                #pragma unroll
                for (int r = 0; r < 4; ++r) {
                    red[(q - 1) * (RT * 128) + (4 * g + r) * 128 + lane]      = acc[r][0];
                    red[(q - 1) * (RT * 128) + (4 * g + r) * 128 + 64 + lane] = acc[r][1];
                }
            }
            __syncthreads();
            if (q == 0) {  // reduce + neuron update (state owner)
                #pragma unroll
                for (int r = 0; r < 4; ++r) {
                    float a0 = acc[r][0], a1 = acc[r][1];
                    #pragma unroll
                    for (int p = 0; p < 3; ++p) {
                        a0 += red[p * (RT * 128) + (4 * g + r) * 128 + lane];
                        a1 += red[p * (RT * 128) + (4 * g + r) * 128 + 64 + lane];
                    }
                    float in0  = (a0 + b1_0) + i1[r][0] * 0.9f;
                    float out0 = fmaxf(in0 - 1.0f, 0.0f);
                    in0 = (out0 > 0.0f) ? (in0 - 1.5f * in0) : in0;
                    i1[r][0] = in0;
                    o1s[(4 * g + r) * H1 + h0] = out0;

                    float in1  = (a1 + b1_1) + i1[r][1] * 0.9f;
                    float out1 = fmaxf(in1 - 1.0f, 0.0f);
                    in1 = (out1 > 0.0f) ? (in1 - 1.5f * in1) : in1;
                    i1[r][1] = in1;
                    if (h1v) o1s[(4 * g + r) * H1 + h1] = out1;
                }
            }
        }
        __syncthreads();
    }

    // ---- epilogue: log_softmax ----
    if (l2act) sums[r2 * H2 + c2] = sum2;
    __syncthreads();
    if (l2act) {
        float m = -INFINITY;
        #pragma unroll
        for (int cc = 0; cc < H2; ++cc) m = fmaxf(m, sums[r2 * H2 + cc]);
        float s = 0.0f;
        #pragma unroll
        for (int cc = 0; cc < H2; ++cc) s += expf(sums[r2 * H2 + cc] - m);
        out[(row0 + r2) * H2 + c2] = sum2 - m - logf(s);
    }
}

extern "C" void kernel_launch(void* const* d_in, const int* in_sizes, int n_in,
                              void* d_out, int out_size, void* d_ws, size_t ws_size,
                              hipStream_t stream) {
    const float* x  = (const float*)d_in[0];
    const float* W1 = (const float*)d_in[1];
    const float* b1 = (const float*)d_in[2];
    const float* W2 = (const float*)d_in[3];
    const float* b2 = (const float*)d_in[4];
    float* out = (float*)d_out;
    float* w1t = (float*)d_ws;                      // 784*100*4 = 313.6 KB scratch

    hipLaunchKernelGGL(transpose_w1, dim3((NIN * H1 + 255) / 256), dim3(256), 0, stream,
                       W1, w1t);
    // 256 blocks x 1024 threads: block owns 16 rows; 16 waves = 4 row-groups x 4 jj-quarters
    hipLaunchKernelGGL(spiking_net_kernel, dim3(BATCH / RT), dim3(1024), 0, stream,
                       x, w1t, b1, W2, b2, out);
}